// Round 1
// baseline (888.085 us; speedup 1.0000x reference)
//
#include <hip/hip_runtime.h>

// LSTM: B=8192, T=256, I=1, H=50, O=1. PyTorch gate order (i,f,g,o).
// Batch-parallel: each block owns 20 batches for all 256 steps; h exchanged
// via double-buffered LDS, one barrier per step. fp32 VALU (no fp32 MFMA on CDNA4).

#define HID 50
#define TSTEPS 256
#define BATCH 8192
#define BG 5            // batch groups per block
#define RB 4            // batches per thread (float4 micro-tile)
#define BPB (BG * RB)   // 20 batches per block
#define NTHREADS 256

__device__ __forceinline__ float sigm(float v) {
    // 1/(1+e^-v): v->+inf: 1/1=1; v->-inf: rcp(inf)=0. Safe.
    return __builtin_amdgcn_rcpf(1.0f + __expf(-v));
}
__device__ __forceinline__ float tanh_fast(float v) {
    // 1 - 2/(e^{2v}+1): v->+inf: 1-0=1; v->-inf: 1-2=-1. Safe.
    float e = __expf(2.0f * v);
    return 1.0f - 2.0f * __builtin_amdgcn_rcpf(e + 1.0f);
}

__global__ __launch_bounds__(NTHREADS) void lstm_kernel(
    const float* __restrict__ x,      // [B][T]
    const float* __restrict__ W_ih,   // [200] (I=1)
    const float* __restrict__ W_hh,   // [200][50]
    const float* __restrict__ b_ih,   // [200]
    const float* __restrict__ b_hh,   // [200]
    const float* __restrict__ W_lin,  // [50]
    const float* __restrict__ b_lin,  // [1]
    float* __restrict__ out)          // [B]
{
    // Wg[k][j] = {W_hh[i-row j][k], W_hh[f-row j][k], W_hh[g-row j][k], W_hh[o-row j][k]}
    __shared__ float4 Wg[HID][HID];
    // double-buffered h, [buf][unit][batch-group(+1 pad slot for inactive lanes)]
    __shared__ float4 hb[2][HID][BG + 1];

    const int tid = threadIdx.x;
    const int j   = tid % HID;      // hidden unit (threads 250..255: duplicate j, bg=5 pad)
    const int bg  = tid / HID;      // 0..5 (5 = inactive pad group)
    const int bbase = (int)blockIdx.x * BPB;
    const int b0  = bbase + bg * RB;

    // --- stage gate-interleaved W_hh into LDS (one-time; L2-cached across blocks)
    for (int idx = tid; idx < HID * HID; idx += NTHREADS) {
        int k = idx / HID, jj = idx % HID;
        float4 w;
        w.x = W_hh[(0 * HID + jj) * HID + k];
        w.y = W_hh[(1 * HID + jj) * HID + k];
        w.z = W_hh[(2 * HID + jj) * HID + k];
        w.w = W_hh[(3 * HID + jj) * HID + k];
        Wg[k][jj] = w;
    }
    // zero both h buffers (h0 = 0; buf1 cleared so pad lanes never see NaN LDS)
    for (int idx = tid; idx < 2 * HID * (BG + 1); idx += NTHREADS) {
        ((float4*)hb)[idx] = make_float4(0.f, 0.f, 0.f, 0.f);
    }

    // per-thread constants for unit j
    float4 wih, bias;
    wih.x  = W_ih[0 * HID + j];
    wih.y  = W_ih[1 * HID + j];
    wih.z  = W_ih[2 * HID + j];
    wih.w  = W_ih[3 * HID + j];
    bias.x = b_ih[0 * HID + j] + b_hh[0 * HID + j];
    bias.y = b_ih[1 * HID + j] + b_hh[1 * HID + j];
    bias.z = b_ih[2 * HID + j] + b_hh[2 * HID + j];
    bias.w = b_ih[3 * HID + j] + b_hh[3 * HID + j];

    float c[RB] = {0.f, 0.f, 0.f, 0.f};

    // x prefetch for t=0 (strided per batch; same addr across j-lanes -> 1 req/group)
    float xv[RB];
    #pragma unroll
    for (int r = 0; r < RB; ++r) {
        int b = b0 + r;
        xv[r] = (b < BATCH) ? x[b * TSTEPS + 0] : 0.f;
    }

    __syncthreads();

    for (int t = 0; t < TSTEPS; ++t) {
        const int cur = t & 1;
        float a[4][RB];
        #pragma unroll
        for (int r = 0; r < RB; ++r) {
            a[0][r] = bias.x + xv[r] * wih.x;
            a[1][r] = bias.y + xv[r] * wih.y;
            a[2][r] = bias.z + xv[r] * wih.z;
            a[3][r] = bias.w + xv[r] * wih.w;
        }

        // 4 gates x 4 batches outer product over k: 2 ds_read_b128 per 16 FMA
        #pragma unroll 10
        for (int k = 0; k < HID; ++k) {
            float4 w = Wg[k][j];
            float4 h = hb[cur][k][bg];
            a[0][0] += w.x * h.x; a[0][1] += w.x * h.y; a[0][2] += w.x * h.z; a[0][3] += w.x * h.w;
            a[1][0] += w.y * h.x; a[1][1] += w.y * h.y; a[1][2] += w.y * h.z; a[1][3] += w.y * h.w;
            a[2][0] += w.z * h.x; a[2][1] += w.z * h.y; a[2][2] += w.z * h.z; a[2][3] += w.z * h.w;
            a[3][0] += w.w * h.x; a[3][1] += w.w * h.y; a[3][2] += w.w * h.z; a[3][3] += w.w * h.w;
        }

        // prefetch next x while activations run
        const int tn = (t + 1 < TSTEPS) ? (t + 1) : (TSTEPS - 1);
        float xn[RB];
        #pragma unroll
        for (int r = 0; r < RB; ++r) {
            int b = b0 + r;
            xn[r] = (b < BATCH) ? x[b * TSTEPS + tn] : 0.f;
        }

        float hnew[RB];
        #pragma unroll
        for (int r = 0; r < RB; ++r) {
            float ig = sigm(a[0][r]);
            float fg = sigm(a[1][r]);
            float gg = tanh_fast(a[2][r]);
            float og = sigm(a[3][r]);
            c[r] = fg * c[r] + ig * gg;
            hnew[r] = og * tanh_fast(c[r]);
        }
        hb[cur ^ 1][j][bg] = make_float4(hnew[0], hnew[1], hnew[2], hnew[3]);

        #pragma unroll
        for (int r = 0; r < RB; ++r) xv[r] = xn[r];

        __syncthreads();
    }

    // epilogue: h_256 lives in hb[0] (last write: t=255 -> buf (255&1)^1 = 0)
    const int nb = (BATCH - bbase < BPB) ? (BATCH - bbase) : BPB;
    if (tid < nb) {
        const int bgE = tid / RB, rE = tid % RB;
        const float* hf = (const float*)&hb[0][0][0];
        float s = b_lin[0];
        #pragma unroll 10
        for (int k = 0; k < HID; ++k)
            s += hf[(k * (BG + 1) + bgE) * 4 + rE] * W_lin[k];
        out[bbase + tid] = s;
    }
}

extern "C" void kernel_launch(void* const* d_in, const int* in_sizes, int n_in,
                              void* d_out, int out_size, void* d_ws, size_t ws_size,
                              hipStream_t stream) {
    const float* x     = (const float*)d_in[0];
    const float* W_ih  = (const float*)d_in[1];
    const float* W_hh  = (const float*)d_in[2];
    const float* b_ih  = (const float*)d_in[3];
    const float* b_hh  = (const float*)d_in[4];
    const float* W_lin = (const float*)d_in[5];
    const float* b_lin = (const float*)d_in[6];
    float* out = (float*)d_out;

    const int nblocks = (BATCH + BPB - 1) / BPB;  // 410
    lstm_kernel<<<dim3(nblocks), dim3(NTHREADS), 0, stream>>>(
        x, W_ih, W_hh, b_ih, b_hh, W_lin, b_lin, out);
}

// Round 3
// 315.431 us; speedup vs baseline: 2.8155x; 2.8155x over previous
//
#include <hip/hip_runtime.h>

// LSTM B=8192,T=256,I=1,H=50 via MFMA. Per block: 16 batches, 256 threads
// (wave w = gate w). Per step: gates[16x256] = A[16x64] x B[64x256] bf16
// MFMA (hi/lo split, 3 products ~ fp32), K-cols 50/51 carry x and bias.
// Elementwise phase: activations, c in fp32 regs, hnew -> LDS as bf16 hi+lo.
// R2 bug: W_hh is 200x50=10000 floats; LDS staging only copied 2500 and
// indexed OOB. R3: build B frags by direct global reads (L2-cached, one-time).

#define MB 16          // batches per block
#define NTH 256
#define TST 256
#define NBLK 512
#define GR 260         // gates LDS row stride (floats), 16x260
#define HR 72          // hA row stride (shorts): 64 + 8 pad

typedef __attribute__((ext_vector_type(8))) short short8;
typedef __attribute__((ext_vector_type(4))) short short4v;
typedef __attribute__((ext_vector_type(4))) float float4v;

__device__ __forceinline__ unsigned short bfhi(float v) {
    return (unsigned short)(__float_as_uint(v) >> 16);  // truncate; lo catches rest
}
__device__ __forceinline__ float bfup(unsigned short u) {
    return __uint_as_float(((unsigned int)u) << 16);
}
__device__ __forceinline__ float sigm(float v) {
    return __builtin_amdgcn_rcpf(1.0f + __expf(-v));
}
__device__ __forceinline__ float tanh_fast(float v) {
    float e = __expf(2.0f * v);
    return 1.0f - 2.0f * __builtin_amdgcn_rcpf(e + 1.0f);
}

__global__ __launch_bounds__(NTH) void lstm_mfma(
    const float* __restrict__ x,      // [8192][256]
    const float* __restrict__ W_ih,   // [200]
    const float* __restrict__ W_hh,   // [200][50]  (10000 floats!)
    const float* __restrict__ b_ih,   // [200]
    const float* __restrict__ b_hh,   // [200]
    const float* __restrict__ W_lin,  // [50]
    const float* __restrict__ b_lin,  // [1]
    float* __restrict__ out)          // [8192]
{
    __shared__ __align__(16) float gates[MB * GR];           // 16.6 KB, C output
    __shared__ __align__(16) unsigned short hA[2 * MB * HR]; // bf16 hi/lo planes
    __shared__ __align__(16) float xs[64 * 17];              // x chunk [64 t][16 b + pad]

    const int tid  = threadIdx.x;
    const int wv   = tid >> 6;     // wave = gate index (i,f,g,o)
    const int ln   = tid & 63;
    const int lrow = ln & 15;      // A-frag row / B-frag col
    const int quad = ln >> 4;
    const int bbase = (int)blockIdx.x * MB;

    // ---- build B fragments directly from global (one-time, L2-cached).
    // B[k][n], n = wv*64 + j; k=50 -> W_ih col, k=51 -> bias col.
    // frag lane layout: col j = tt*16 + (ln&15), k = q*32 + quad*8 + i
    short8 wh[4][2], wl[4][2];
    #pragma unroll
    for (int tt = 0; tt < 4; ++tt) {
        const int j = tt * 16 + lrow;
        #pragma unroll
        for (int q = 0; q < 2; ++q) {
            short8 h8, l8;
            #pragma unroll
            for (int i = 0; i < 8; ++i) {
                const int k = q * 32 + quad * 8 + i;
                float V = 0.0f;
                if (j < 50) {
                    const int row = wv * 50 + j;     // 0..199
                    if (k < 50)       V = W_hh[row * 50 + k];
                    else if (k == 50) V = W_ih[row];
                    else if (k == 51) V = b_ih[row] + b_hh[row];
                }
                unsigned short hb = bfhi(V);
                h8[i] = (short)hb;
                l8[i] = (short)bfhi(V - bfup(hb));
            }
            wh[tt][q] = h8;
            wl[tt][q] = l8;
        }
    }

    // ---- init hA = 0, then slots: [b][50] = x(b,0) hi/lo, [b][51] = 1.0 ----
    for (int i = tid; i < 2 * MB * HR; i += NTH) hA[i] = 0;
    __syncthreads();
    if (tid < MB) {
        const int b = tid;
        float xv = x[(bbase + b) * TST + 0];
        unsigned short xh = bfhi(xv);
        hA[0 * MB * HR + b * HR + 50] = xh;
        hA[1 * MB * HR + b * HR + 50] = bfhi(xv - bfup(xh));
        hA[0 * MB * HR + b * HR + 51] = 0x3F80;  // bf16(1.0)
    }
    // stage xs chunk 0: x indices [0..64)
    {
        const int b = tid & 15, i0 = (tid >> 4) * 4;
        const float4* xp = (const float4*)&x[(bbase + b) * TST + i0];
        float4 xv4 = *xp;
        xs[(i0 + 0) * 17 + b] = xv4.x;
        xs[(i0 + 1) * 17 + b] = xv4.y;
        xs[(i0 + 2) * 17 + b] = xv4.z;
        xs[(i0 + 3) * 17 + b] = xv4.w;
    }
    float c0 = 0.f, c1 = 0.f, c2 = 0.f, c3 = 0.f;
    __syncthreads();

    const int u  = tid >> 4;      // elementwise: unit group (j0 = 4u)
    const int eb = tid & 15;      // elementwise: batch
    const int j0 = u * 4;

    for (int t = 0; t < TST; ++t) {
        // restage next x chunk at t = 63,127,191 (consumed after barrier1)
        if (((t & 63) == 63) && t != 255) {
            const int b = tid & 15, i0 = (tid >> 4) * 4;
            const float4* xp = (const float4*)&x[(bbase + b) * TST + (t + 1) + i0];
            float4 xv4 = *xp;
            xs[(i0 + 0) * 17 + b] = xv4.x;
            xs[(i0 + 1) * 17 + b] = xv4.y;
            xs[(i0 + 2) * 17 + b] = xv4.z;
            xs[(i0 + 3) * 17 + b] = xv4.w;
        }

        // ---- GEMM: read A frags (h hi/lo), 24 MFMA, write C to gates LDS ----
        const short8 ah0 = *(const short8*)&hA[0 * MB * HR + lrow * HR + quad * 8];
        const short8 ah1 = *(const short8*)&hA[0 * MB * HR + lrow * HR + 32 + quad * 8];
        const short8 al0 = *(const short8*)&hA[1 * MB * HR + lrow * HR + quad * 8];
        const short8 al1 = *(const short8*)&hA[1 * MB * HR + lrow * HR + 32 + quad * 8];

        #pragma unroll
        for (int tt = 0; tt < 4; ++tt) {
            float4v acc = {0.f, 0.f, 0.f, 0.f};
            acc = __builtin_amdgcn_mfma_f32_16x16x32_bf16(ah0, wh[tt][0], acc, 0, 0, 0);
            acc = __builtin_amdgcn_mfma_f32_16x16x32_bf16(ah1, wh[tt][1], acc, 0, 0, 0);
            acc = __builtin_amdgcn_mfma_f32_16x16x32_bf16(al0, wh[tt][0], acc, 0, 0, 0);
            acc = __builtin_amdgcn_mfma_f32_16x16x32_bf16(al1, wh[tt][1], acc, 0, 0, 0);
            acc = __builtin_amdgcn_mfma_f32_16x16x32_bf16(ah0, wl[tt][0], acc, 0, 0, 0);
            acc = __builtin_amdgcn_mfma_f32_16x16x32_bf16(ah1, wl[tt][1], acc, 0, 0, 0);
            // C/D: row = quad*4 + r, col = ln&15  ->  gates[row][wv*64 + tt*16 + col]
            #pragma unroll
            for (int r = 0; r < 4; ++r)
                gates[(quad * 4 + r) * GR + wv * 64 + tt * 16 + lrow] = acc[r];
        }
        __syncthreads();  // barrier1: gates ready

        // ---- elementwise: 4 units x 1 batch per thread ----
        if (u <= 12) {
            const float4v gi = *(const float4v*)&gates[eb * GR + 0 * 64 + j0];
            const float4v gf = *(const float4v*)&gates[eb * GR + 1 * 64 + j0];
            const float4v gg = *(const float4v*)&gates[eb * GR + 2 * 64 + j0];
            const float4v go = *(const float4v*)&gates[eb * GR + 3 * 64 + j0];

            float h0, h1, h2, h3;
            {
                float i_ = sigm(gi[0]), f_ = sigm(gf[0]), g_ = tanh_fast(gg[0]), o_ = sigm(go[0]);
                c0 = f_ * c0 + i_ * g_;  h0 = o_ * tanh_fast(c0);
            }
            {
                float i_ = sigm(gi[1]), f_ = sigm(gf[1]), g_ = tanh_fast(gg[1]), o_ = sigm(go[1]);
                c1 = f_ * c1 + i_ * g_;  h1 = o_ * tanh_fast(c1);
            }
            {
                float i_ = sigm(gi[2]), f_ = sigm(gf[2]), g_ = tanh_fast(gg[2]), o_ = sigm(go[2]);
                c2 = f_ * c2 + i_ * g_;  h2 = o_ * tanh_fast(c2);
            }
            {
                float i_ = sigm(gi[3]), f_ = sigm(gf[3]), g_ = tanh_fast(gg[3]), o_ = sigm(go[3]);
                c3 = f_ * c3 + i_ * g_;  h3 = o_ * tanh_fast(c3);
            }
            // pad units (u==12, m=2,3): gates are exactly 0 there, c stays 0, h=0 — safe,
            // but we overwrite those slots with x(t+1) and the bias-one column.
            short4v hv, lv;
            hv[0] = (short)bfhi(h0); lv[0] = (short)bfhi(h0 - bfup((unsigned short)hv[0]));
            hv[1] = (short)bfhi(h1); lv[1] = (short)bfhi(h1 - bfup((unsigned short)hv[1]));
            hv[2] = (short)bfhi(h2); lv[2] = (short)bfhi(h2 - bfup((unsigned short)hv[2]));
            hv[3] = (short)bfhi(h3); lv[3] = (short)bfhi(h3 - bfup((unsigned short)hv[3]));
            if (u == 12) {
                float xv = xs[((t + 1) & 63) * 17 + eb];
                unsigned short xh = bfhi(xv);
                hv[2] = (short)xh; lv[2] = (short)bfhi(xv - bfup(xh));
                hv[3] = (short)0x3F80; lv[3] = 0;
            }
            *(short4v*)&hA[0 * MB * HR + eb * HR + j0] = hv;
            *(short4v*)&hA[1 * MB * HR + eb * HR + j0] = lv;
        }
        __syncthreads();  // barrier2: hA ready for next step
    }

    // ---- epilogue: out[b] = b_lin + sum_k h[b][k] * W_lin[k] ----
    if (tid < MB) {
        const int b = tid;
        float s = b_lin[0];
        #pragma unroll 10
        for (int k = 0; k < 50; ++k) {
            float hk = bfup(hA[0 * MB * HR + b * HR + k]) + bfup(hA[1 * MB * HR + b * HR + k]);
            s += hk * W_lin[k];
        }
        out[bbase + b] = s;
    }
}

extern "C" void kernel_launch(void* const* d_in, const int* in_sizes, int n_in,
                              void* d_out, int out_size, void* d_ws, size_t ws_size,
                              hipStream_t stream) {
    const float* x     = (const float*)d_in[0];
    const float* W_ih  = (const float*)d_in[1];
    const float* W_hh  = (const float*)d_in[2];
    const float* b_ih  = (const float*)d_in[3];
    const float* b_hh  = (const float*)d_in[4];
    const float* W_lin = (const float*)d_in[5];
    const float* b_lin = (const float*)d_in[6];
    float* out = (float*)d_out;

    lstm_mfma<<<dim3(NBLK), dim3(NTH), 0, stream>>>(
        x, W_ih, W_hh, b_ih, b_hh, W_lin, b_lin, out);
}